// Round 2
// baseline (1377.256 us; speedup 1.0000x reference)
//
#include <hip/hip_runtime.h>
#include <hip/hip_bf16.h>
#include <math.h>

// Problem constants
static constexpr int BB  = 4;
static constexpr int S   = 2048;
static constexpr int D   = 512;
static constexpr int DFF = 2048;
static constexpr int BS  = BB * S;   // 8192 rows

// ---- block-wide reductions (block = 256 threads = 4 waves of 64) ----
__device__ __forceinline__ float blockSum(float v) {
#pragma unroll
  for (int o = 32; o; o >>= 1) v += __shfl_xor(v, o, 64);
  __shared__ float t[4];
  __syncthreads();                       // protect reuse across calls
  if ((threadIdx.x & 63) == 0) t[threadIdx.x >> 6] = v;
  __syncthreads();
  return t[0] + t[1] + t[2] + t[3];
}

__device__ __forceinline__ float blockMax(float v) {
#pragma unroll
  for (int o = 32; o; o >>= 1) v = fmaxf(v, __shfl_xor(v, o, 64));
  __shared__ float t[4];
  __syncthreads();
  if ((threadIdx.x & 63) == 0) t[threadIdx.x >> 6] = v;
  __syncthreads();
  return fmaxf(fmaxf(t[0], t[1]), fmaxf(t[2], t[3]));
}

// ---- 1. embedding gather + positional encoding + sqrt(D) scale ----
// ang = pos / 10000^(2*i/D); sin for even i, cos for odd i.
__global__ __launch_bounds__(256) void embed_pos_k(
    const int* __restrict__ seq, const float* __restrict__ emb,
    float* __restrict__ X) {
  const int bs = blockIdx.x;
  const int s  = bs & (S - 1);
  const int idx = seq[bs];
  const float* er = emb + (size_t)idx * D;
  float* xr = X + (size_t)bs * D;
#pragma unroll
  for (int t = 0; t < 2; ++t) {
    const int d = threadIdx.x + 256 * t;
    const double ang = (double)s / pow(10000.0, (2.0 * d) / (double)D);
    const float p = (d & 1) ? (float)cos(ang) : (float)sin(ang);
    xr[d] = (er[d] + p) * 22.62741699796952f;  // * sqrt(512)
  }
}

// ---- 2. generic fp32 tiled GEMM ----
// C[M,N] = act( scale * A[M,K] @ op(B) + bias ), batched via blockIdx.z.
// TRB=false: B is [K,N]; TRB=true: B is [N,K] (used for k @ q^T).
// ACT: 0=none, 1=exact GELU.
// 64x64 tile, BK=16, 256 threads, 4x4 micro-tile per thread.
template <bool TRB, int ACT>
__global__ __launch_bounds__(256) void gemm_k(
    const float* __restrict__ A, const float* __restrict__ B,
    float* __restrict__ C, const float* __restrict__ bias,
    int M, int N, int K, long sA, long sB, long sC, float scale) {
  A += (long)blockIdx.z * sA;
  B += (long)blockIdx.z * sB;
  C += (long)blockIdx.z * sC;
  const int n0 = blockIdx.x * 64, m0 = blockIdx.y * 64;
  __shared__ float As[16][64];
  __shared__ float Bsh[16][64];
  const int tid = threadIdx.x;
  const int tx = tid & 15, ty = tid >> 4;
  float acc[4][4] = {};

  for (int k0 = 0; k0 < K; k0 += 16) {
    {  // A tile: 64 rows x 16 k, float4 per thread
      const int r = tid >> 2, c = (tid & 3) << 2;
      const float4 a4 = *(const float4*)(A + (long)(m0 + r) * K + k0 + c);
      As[c + 0][r] = a4.x; As[c + 1][r] = a4.y;
      As[c + 2][r] = a4.z; As[c + 3][r] = a4.w;
    }
    if constexpr (TRB) {  // B[N,K] -> Bsh[k][n]
      const int r = tid >> 2, c = (tid & 3) << 2;
      const float4 b4 = *(const float4*)(B + (long)(n0 + r) * K + k0 + c);
      Bsh[c + 0][r] = b4.x; Bsh[c + 1][r] = b4.y;
      Bsh[c + 2][r] = b4.z; Bsh[c + 3][r] = b4.w;
    } else {  // B[K,N] -> Bsh[k][n]
      const int r = tid >> 4, c = (tid & 15) << 2;
      const float4 b4 = *(const float4*)(B + (long)(k0 + r) * N + n0 + c);
      Bsh[r][c + 0] = b4.x; Bsh[r][c + 1] = b4.y;
      Bsh[r][c + 2] = b4.z; Bsh[r][c + 3] = b4.w;
    }
    __syncthreads();
#pragma unroll
    for (int kk = 0; kk < 16; ++kk) {
      const float4 a4 = *(const float4*)&As[kk][ty << 2];
      const float4 b4 = *(const float4*)&Bsh[kk][tx << 2];
      const float av[4] = {a4.x, a4.y, a4.z, a4.w};
      const float bv[4] = {b4.x, b4.y, b4.z, b4.w};
#pragma unroll
      for (int i = 0; i < 4; ++i)
#pragma unroll
        for (int j = 0; j < 4; ++j) acc[i][j] += av[i] * bv[j];
    }
    __syncthreads();
  }

  float bv[4] = {0.f, 0.f, 0.f, 0.f};
  if (bias) {
#pragma unroll
    for (int j = 0; j < 4; ++j) bv[j] = bias[n0 + (tx << 2) + j];
  }
#pragma unroll
  for (int i = 0; i < 4; ++i) {
    float4 o;
    float* op = &o.x;
#pragma unroll
    for (int j = 0; j < 4; ++j) {
      float cv = acc[i][j] * scale + bv[j];
      if constexpr (ACT == 1)
        cv = 0.5f * cv * (1.0f + erff(cv * 0.7071067811865476f));
      op[j] = cv;
    }
    *(float4*)(C + (long)(m0 + (ty << 2) + i) * N + n0 + (tx << 2)) = o;
  }
}

// ---- 3. row softmax over S=2048, in place ----
__global__ __launch_bounds__(256) void softmax_k(float* __restrict__ Sc) {
  float* p = Sc + (size_t)blockIdx.x * S;
  const int tid = threadIdx.x;
  float v[8];
  float m = -1e30f;
#pragma unroll
  for (int i = 0; i < 8; ++i) { v[i] = p[tid + 256 * i]; m = fmaxf(m, v[i]); }
  m = blockMax(m);
  float sum = 0.f;
#pragma unroll
  for (int i = 0; i < 8; ++i) { v[i] = expf(v[i] - m); sum += v[i]; }
  sum = blockSum(sum);
  const float inv = 1.0f / sum;
#pragma unroll
  for (int i = 0; i < 8; ++i) p[tid + 256 * i] = v[i] * inv;
}

// ---- 4. r = LayerNorm(X + Add) written back into X (in-place) ----
__global__ __launch_bounds__(256) void ln_res_k(
    float* __restrict__ X, const float* __restrict__ Add,
    const float* __restrict__ g, const float* __restrict__ b) {
  float* xr = X + (size_t)blockIdx.x * D;
  const float* ar = Add + (size_t)blockIdx.x * D;
  const int t0 = threadIdx.x, t1 = threadIdx.x + 256;
  const float z0 = xr[t0] + ar[t0];
  const float z1 = xr[t1] + ar[t1];
  const float mu = blockSum(z0 + z1) * (1.0f / D);
  const float d0 = z0 - mu, d1 = z1 - mu;
  const float var = blockSum(d0 * d0 + d1 * d1) * (1.0f / D);
  const float rs = rsqrtf(var + 1e-5f);
  xr[t0] = d0 * rs * g[t0] + b[t0];
  xr[t1] = d1 * rs * g[t1] + b[t1];
}

// ---- 5. out = LayerNorm(R + F) ----
__global__ __launch_bounds__(256) void ln_out_k(
    const float* __restrict__ R, const float* __restrict__ F,
    const float* __restrict__ g, const float* __restrict__ b,
    float* __restrict__ out) {
  const float* rr = R + (size_t)blockIdx.x * D;
  const float* fr = F + (size_t)blockIdx.x * D;
  float* orow = out + (size_t)blockIdx.x * D;
  const int t0 = threadIdx.x, t1 = threadIdx.x + 256;
  const float z0 = rr[t0] + fr[t0];
  const float z1 = rr[t1] + fr[t1];
  const float mu = blockSum(z0 + z1) * (1.0f / D);
  const float d0 = z0 - mu, d1 = z1 - mu;
  const float var = blockSum(d0 * d0 + d1 * d1) * (1.0f / D);
  const float rs = rsqrtf(var + 1e-5f);
  orow[t0] = d0 * rs * g[t0] + b[t0];
  orow[t1] = d1 * rs * g[t1] + b[t1];
}

extern "C" void kernel_launch(void* const* d_in, const int* in_sizes, int n_in,
                              void* d_out, int out_size, void* d_ws, size_t ws_size,
                              hipStream_t stream) {
  (void)in_sizes; (void)n_in; (void)out_size; (void)ws_size;
  const int*   seq = (const int*)d_in[0];
  const float* emb = (const float*)d_in[1];
  const float* wk  = (const float*)d_in[2];
  const float* bk  = (const float*)d_in[3];
  const float* wq  = (const float*)d_in[4];
  const float* bq  = (const float*)d_in[5];
  const float* wv  = (const float*)d_in[6];
  const float* bv  = (const float*)d_in[7];
  const float* lng = (const float*)d_in[8];
  const float* lnb = (const float*)d_in[9];
  const float* w1  = (const float*)d_in[10];
  const float* b1  = (const float*)d_in[11];
  const float* w2  = (const float*)d_in[12];
  const float* b2  = (const float*)d_in[13];

  // Workspace layout (fp32), 128 MB total, with reuse:
  //   X  : x, later r (LN in-place)
  //   Kb : k, later ff2 output
  //   Qb : q, later attn output
  //   Vb : v
  //   Sc : scores [B,S,S], later FF hidden h [BS,DFF]
  float* X  = (float*)d_ws;
  float* Kb = X  + (size_t)BS * D;
  float* Qb = Kb + (size_t)BS * D;
  float* Vb = Qb + (size_t)BS * D;
  float* Sc = Vb + (size_t)BS * D;   // 16M floats

  const long SD = (long)S * D;
  const long SS = (long)S * S;
  const float iscale = 0.044194173824159216f;  // 1/sqrt(512)

  embed_pos_k<<<BS, 256, 0, stream>>>(seq, emb, X);

  // k/q/v projections: [8192,512] @ [512,512] + bias
  gemm_k<false, 0><<<dim3(D / 64, BS / 64, 1), 256, 0, stream>>>(
      X, wk, Kb, bk, BS, D, D, 0, 0, 0, 1.0f);
  gemm_k<false, 0><<<dim3(D / 64, BS / 64, 1), 256, 0, stream>>>(
      X, wq, Qb, bq, BS, D, D, 0, 0, 0, 1.0f);
  gemm_k<false, 0><<<dim3(D / 64, BS / 64, 1), 256, 0, stream>>>(
      X, wv, Vb, bv, BS, D, D, 0, 0, 0, 1.0f);

  // scores = (k @ q^T) / sqrt(D)   [batched over B]
  gemm_k<true, 0><<<dim3(S / 64, S / 64, BB), 256, 0, stream>>>(
      Kb, Qb, Sc, nullptr, S, S, D, SD, SD, SS, iscale);

  softmax_k<<<BS, 256, 0, stream>>>(Sc);

  // attn = P @ v -> Qb   [batched]
  gemm_k<false, 0><<<dim3(D / 64, S / 64, BB), 256, 0, stream>>>(
      Sc, Vb, Qb, nullptr, S, D, S, SS, SD, SD, 1.0f);

  // r = LN(x + attn) -> X (in place)
  ln_res_k<<<BS, 256, 0, stream>>>(X, Qb, lng, lnb);

  // h = gelu(r @ w1 + b1) -> Sc
  gemm_k<false, 1><<<dim3(DFF / 64, BS / 64, 1), 256, 0, stream>>>(
      X, w1, Sc, b1, BS, DFF, D, 0, 0, 0, 1.0f);

  // ff = h @ w2 + b2 -> Kb
  gemm_k<false, 0><<<dim3(D / 64, BS / 64, 1), 256, 0, stream>>>(
      Sc, w2, Kb, b2, BS, D, DFF, 0, 0, 0, 1.0f);

  // out = LN(r + ff)
  ln_out_k<<<BS, 256, 0, stream>>>(X, Kb, lng, lnb, (float*)d_out);
}

// Round 3
// 573.175 us; speedup vs baseline: 2.4029x; 2.4029x over previous
//
#include <hip/hip_runtime.h>
#include <math.h>

static constexpr int BB  = 4;
static constexpr int S   = 2048;
static constexpr int D   = 512;
static constexpr int DFF = 2048;
static constexpr int BS  = BB * S;   // 8192 rows

using u16 = unsigned short;
using v8s = __attribute__((ext_vector_type(8))) short;
using v4s = __attribute__((ext_vector_type(4))) short;
using v4f = __attribute__((ext_vector_type(4))) float;

__device__ __forceinline__ float bf2f(u16 h) {
  union { unsigned int u; float f; } c; c.u = ((unsigned int)h) << 16; return c.f;
}
__device__ __forceinline__ u16 f2bf(float f) {  // round-to-nearest-even
  union { float f; unsigned int u; } c; c.f = f;
  unsigned int r = c.u + 0x7FFF + ((c.u >> 16) & 1);
  return (u16)(r >> 16);
}

// ---- block-wide reductions (block = 256 threads = 4 waves) ----
__device__ __forceinline__ float blockSum(float v) {
#pragma unroll
  for (int o = 32; o; o >>= 1) v += __shfl_xor(v, o, 64);
  __shared__ float t[4];
  __syncthreads();
  if ((threadIdx.x & 63) == 0) t[threadIdx.x >> 6] = v;
  __syncthreads();
  return t[0] + t[1] + t[2] + t[3];
}
__device__ __forceinline__ float blockMax(float v) {
#pragma unroll
  for (int o = 32; o; o >>= 1) v = fmaxf(v, __shfl_xor(v, o, 64));
  __shared__ float t[4];
  __syncthreads();
  if ((threadIdx.x & 63) == 0) t[threadIdx.x >> 6] = v;
  __syncthreads();
  return fmaxf(fmaxf(t[0], t[1]), fmaxf(t[2], t[3]));
}

// ---- embedding gather + positional encoding; writes fp32 + bf16 hi/lo split ----
__global__ __launch_bounds__(256) void embed_pos_k(
    const int* __restrict__ seq, const float* __restrict__ emb,
    float* __restrict__ X, u16* __restrict__ Xhi, u16* __restrict__ Xlo) {
  const int bs = blockIdx.x;
  const int s  = bs & (S - 1);
  const int idx = seq[bs];
  const float* er = emb + (size_t)idx * D;
#pragma unroll
  for (int t = 0; t < 2; ++t) {
    const int d = threadIdx.x + 256 * t;
    const double ang = (double)s / pow(10000.0, (2.0 * d) / (double)D);
    const float p = (d & 1) ? (float)cos(ang) : (float)sin(ang);
    const float val = (er[d] + p) * 22.62741699796952f;  // * sqrt(512)
    const size_t o = (size_t)bs * D + d;
    X[o] = val;
    const u16 hi = f2bf(val);
    Xhi[o] = hi;
    Xlo[o] = f2bf(val - bf2f(hi));
  }
}

// ---- weight transpose + bf16 split:  W[K,N] fp32 -> T[N,K] bf16 (hi, optional lo) ----
__global__ __launch_bounds__(256) void wt_k(
    const float* __restrict__ W, u16* __restrict__ Thi, u16* __restrict__ Tlo,
    int K, int N) {
  const int idx = blockIdx.x * 256 + threadIdx.x;
  const int k = idx / N, n = idx % N;
  const float v = W[idx];
  const u16 hi = f2bf(v);
  Thi[(long)n * K + k] = hi;
  if (Tlo) Tlo[(long)n * K + k] = f2bf(v - bf2f(hi));
}

// ---- MFMA GEMM: C[M,N] = act(scale * A[M,K] @ B^T + bias), B given as [N,K] ----
// AMODE: 0 = bf16, 1 = bf16 hi/lo split (lo at A+aLo), 2 = fp32 source (convert in staging)
// BMODE: 0 = bf16, 1 = bf16 hi/lo split (lo at B+bLo)
// OMODE: 0 = fp32, 1 = bf16, 2 = bf16 hi/lo split (lo at C+cLo), 3 = bf16 transposed
//        per-batch (vT[z][n][m], z = gm>>11) for the V projection
// ACT:   0 = none, 1 = exact GELU
// Tile 128x128, BK=32, 256 threads (4 waves, each 64x64 via 4x4 16x16x32 MFMA).
template <int AMODE, int BMODE, int OMODE, int ACT>
__global__ __launch_bounds__(256) void mm_k(
    const void* __restrict__ Ap_, const void* __restrict__ Bp_,
    void* __restrict__ Cp_, const float* __restrict__ bias,
    int M, int N, int K, long sA, long sB, long sC,
    long aLo, long bLo, long cLo, float scale) {
  constexpr int NA = (AMODE == 1) ? 2 : 1;
  constexpr int NB = (BMODE == 1) ? 2 : 1;
  constexpr int LP = 40;              // LDS row pitch in u16 (80 B: bank-spread, 16B-aligned)
  constexpr int TBUF = 128 * LP;
  __shared__ __align__(16) u16 lds[(NA + NB) * TBUF];
  u16* const Ah = lds;
  u16* const Al = lds + TBUF;
  u16* const Bh = lds + NA * TBUF;
  u16* const Bl = lds + (NA + 1) * TBUF;

  const int tid  = threadIdx.x;
  const int lane = tid & 63;
  const int w = tid >> 6, wm = w >> 1, wn = w & 1;
  const int quad = lane >> 4, l16 = lane & 15;
  const int m0 = blockIdx.y * 128, n0 = blockIdx.x * 128;

  const u16*   Ab = (const u16*)Ap_   + (long)blockIdx.z * sA;
  const float* Af = (const float*)Ap_ + (long)blockIdx.z * sA;
  const u16*   Bb = (const u16*)Bp_   + (long)blockIdx.z * sB;

  v4f acc[4][4] = {};

  const int srow = tid >> 2;          // 0..63
  const int skof = (tid & 3) * 8;     // 0,8,16,24

  for (int k0 = 0; k0 < K; k0 += 32) {
    __syncthreads();
    // ---- stage A tile [128][32] ----
    if constexpr (AMODE == 2) {
#pragma unroll
      for (int it = 0; it < 4; ++it) {
        const int eo = (tid + it * 256) * 4;  // 0..4092
        const int r = eo >> 5, c = eo & 31;
        const float4 f = *(const float4*)(Af + (long)(m0 + r) * K + k0 + c);
        v4s h;
        h[0] = (short)f2bf(f.x); h[1] = (short)f2bf(f.y);
        h[2] = (short)f2bf(f.z); h[3] = (short)f2bf(f.w);
        *(v4s*)&Ah[r * LP + c] = h;
      }
    } else {
#pragma unroll
      for (int it = 0; it < 2; ++it) {
        const int r = srow + it * 64;
        *(v8s*)&Ah[r * LP + skof] =
            *(const v8s*)(Ab + (long)(m0 + r) * K + k0 + skof);
        if constexpr (AMODE == 1)
          *(v8s*)&Al[r * LP + skof] =
              *(const v8s*)(Ab + aLo + (long)(m0 + r) * K + k0 + skof);
      }
    }
    // ---- stage B tile [128][32] (B is [N,K] row-major) ----
#pragma unroll
    for (int it = 0; it < 2; ++it) {
      const int r = srow + it * 64;
      *(v8s*)&Bh[r * LP + skof] =
          *(const v8s*)(Bb + (long)(n0 + r) * K + k0 + skof);
      if constexpr (BMODE == 1)
        *(v8s*)&Bl[r * LP + skof] =
            *(const v8s*)(Bb + bLo + (long)(n0 + r) * K + k0 + skof);
    }
    __syncthreads();

    // ---- fragments + MFMA ----
    v8s af[4], bfr[4], al[4], bl[4];
#pragma unroll
    for (int t = 0; t < 4; ++t) {
      const int ao = (wm * 64 + t * 16 + l16) * LP + quad * 8;
      const int bo = (wn * 64 + t * 16 + l16) * LP + quad * 8;
      af[t]  = *(v8s*)&Ah[ao];
      bfr[t] = *(v8s*)&Bh[bo];
      if constexpr (AMODE == 1) al[t] = *(v8s*)&Al[ao];
      if constexpr (BMODE == 1) bl[t] = *(v8s*)&Bl[bo];
    }
#pragma unroll
    for (int mt = 0; mt < 4; ++mt)
#pragma unroll
      for (int nt = 0; nt < 4; ++nt) {
        acc[mt][nt] = __builtin_amdgcn_mfma_f32_16x16x32_bf16(
            af[mt], bfr[nt], acc[mt][nt], 0, 0, 0);
        if constexpr (AMODE == 1)
          acc[mt][nt] = __builtin_amdgcn_mfma_f32_16x16x32_bf16(
              al[mt], bfr[nt], acc[mt][nt], 0, 0, 0);
        if constexpr (BMODE == 1)
          acc[mt][nt] = __builtin_amdgcn_mfma_f32_16x16x32_bf16(
              af[mt], bl[nt], acc[mt][nt], 0, 0, 0);
      }
  }

  // ---- epilogue (C layout: col = lane&15, row = quad*4 + reg) ----
  const long Cz = (long)blockIdx.z * sC;
#pragma unroll
  for (int nt = 0; nt < 4; ++nt) {
    const int gn = n0 + wn * 64 + nt * 16 + l16;
    const float bv = bias ? bias[gn] : 0.0f;
#pragma unroll
    for (int mt = 0; mt < 4; ++mt) {
      const int gmb = m0 + wm * 64 + mt * 16 + quad * 4;
#pragma unroll
      for (int r = 0; r < 4; ++r) {
        const int gm = gmb + r;
        float v = acc[mt][nt][r] * scale + bv;
        if constexpr (ACT == 1)
          v = 0.5f * v * (1.0f + erff(v * 0.7071067811865476f));
        const long ci = Cz + (long)gm * N + gn;
        if constexpr (OMODE == 0) {
          ((float*)Cp_)[ci] = v;
        } else if constexpr (OMODE == 1) {
          ((u16*)Cp_)[ci] = f2bf(v);
        } else if constexpr (OMODE == 2) {
          const u16 hi = f2bf(v);
          ((u16*)Cp_)[ci] = hi;
          ((u16*)Cp_)[ci + cLo] = f2bf(v - bf2f(hi));
        } else {  // vT[z][gn][ml]
          const int z2 = gm >> 11, ml = gm & 2047;
          ((u16*)Cp_)[((long)z2 * N + gn) * 2048 + ml] = f2bf(v);
        }
      }
    }
  }
}

// ---- row softmax over S=2048, in place, fp32 ----
__global__ __launch_bounds__(256) void softmax_k(float* __restrict__ Sc) {
  float* p = Sc + (size_t)blockIdx.x * S;
  const int tid = threadIdx.x;
  float v[8];
  float m = -1e30f;
#pragma unroll
  for (int i = 0; i < 8; ++i) { v[i] = p[tid + 256 * i]; m = fmaxf(m, v[i]); }
  m = blockMax(m);
  float sum = 0.f;
#pragma unroll
  for (int i = 0; i < 8; ++i) { v[i] = expf(v[i] - m); sum += v[i]; }
  sum = blockSum(sum);
  const float inv = 1.0f / sum;
#pragma unroll
  for (int i = 0; i < 8; ++i) p[tid + 256 * i] = v[i] * inv;
}

// ---- r = LayerNorm(X + Add) -> X (in place) + bf16 copy rB ----
__global__ __launch_bounds__(256) void ln_res_k(
    float* __restrict__ X, const float* __restrict__ Add,
    const float* __restrict__ g, const float* __restrict__ b,
    u16* __restrict__ rB) {
  float* xr = X + (size_t)blockIdx.x * D;
  const float* ar = Add + (size_t)blockIdx.x * D;
  u16* rb = rB + (size_t)blockIdx.x * D;
  const int t0 = threadIdx.x, t1 = threadIdx.x + 256;
  const float z0 = xr[t0] + ar[t0];
  const float z1 = xr[t1] + ar[t1];
  const float mu = blockSum(z0 + z1) * (1.0f / D);
  const float d0 = z0 - mu, d1 = z1 - mu;
  const float var = blockSum(d0 * d0 + d1 * d1) * (1.0f / D);
  const float rs = rsqrtf(var + 1e-5f);
  const float v0 = d0 * rs * g[t0] + b[t0];
  const float v1 = d1 * rs * g[t1] + b[t1];
  xr[t0] = v0; xr[t1] = v1;
  rb[t0] = f2bf(v0); rb[t1] = f2bf(v1);
}

// ---- out = LayerNorm(R + F), fp32 ----
__global__ __launch_bounds__(256) void ln_out_k(
    const float* __restrict__ R, const float* __restrict__ F,
    const float* __restrict__ g, const float* __restrict__ b,
    float* __restrict__ out) {
  const float* rr = R + (size_t)blockIdx.x * D;
  const float* fr = F + (size_t)blockIdx.x * D;
  float* orow = out + (size_t)blockIdx.x * D;
  const int t0 = threadIdx.x, t1 = threadIdx.x + 256;
  const float z0 = rr[t0] + fr[t0];
  const float z1 = rr[t1] + fr[t1];
  const float mu = blockSum(z0 + z1) * (1.0f / D);
  const float d0 = z0 - mu, d1 = z1 - mu;
  const float var = blockSum(d0 * d0 + d1 * d1) * (1.0f / D);
  const float rs = rsqrtf(var + 1e-5f);
  orow[t0] = d0 * rs * g[t0] + b[t0];
  orow[t1] = d1 * rs * g[t1] + b[t1];
}

extern "C" void kernel_launch(void* const* d_in, const int* in_sizes, int n_in,
                              void* d_out, int out_size, void* d_ws, size_t ws_size,
                              hipStream_t stream) {
  (void)in_sizes; (void)n_in; (void)out_size; (void)ws_size;
  const int*   seq = (const int*)d_in[0];
  const float* emb = (const float*)d_in[1];
  const float* wk  = (const float*)d_in[2];
  const float* bk  = (const float*)d_in[3];
  const float* wq  = (const float*)d_in[4];
  const float* bq  = (const float*)d_in[5];
  const float* wv  = (const float*)d_in[6];
  const float* bv  = (const float*)d_in[7];
  const float* lng = (const float*)d_in[8];
  const float* lnb = (const float*)d_in[9];
  const float* w1  = (const float*)d_in[10];
  const float* b1  = (const float*)d_in[11];
  const float* w2  = (const float*)d_in[12];
  const float* b2  = (const float*)d_in[13];

  // 128 MB workspace layout (byte offsets, lifetimes commented):
  //  [0,16)   X fp32 (x, then r via in-place LN)
  //  [16,24)  Xhi bf16            -> rB bf16 after projections
  //  [24,32)  Xlo bf16            -> vT bf16 (v proj runs after k,q proj)
  //  [32,48)  kHi|kLo bf16        -> ff fp32 after scores
  //  [48,64)  qHi|qLo bf16        -> attn fp32 after scores
  //  [64,128) Sc fp32 (softmax in place); pre-scores: proj weight tiles at [64,66.5)
  //           post-PV: hB bf16 [64,96), w1T [96,98), w2T [98,100)
  const size_t MBy = 1024 * 1024;
  char* wsb = (char*)d_ws;
  float* X   = (float*)wsb;
  u16* Xhi  = (u16*)(wsb + 16 * MBy);
  u16* Xlo  = (u16*)(wsb + 24 * MBy);
  u16* kHi  = (u16*)(wsb + 32 * MBy);
  u16* qHi  = (u16*)(wsb + 48 * MBy);
  u16* vT   = (u16*)(wsb + 24 * MBy);
  u16* rB   = (u16*)(wsb + 16 * MBy);
  float* ff   = (float*)(wsb + 32 * MBy);
  float* attn = (float*)(wsb + 48 * MBy);
  float* Sc   = (float*)(wsb + 64 * MBy);
  u16* wkTh = (u16*)(wsb + 64 * MBy);
  u16* wkTl = (u16*)(wsb + 64 * MBy + 512 * 1024);
  u16* wqTh = (u16*)(wsb + 65 * MBy);
  u16* wqTl = (u16*)(wsb + 65 * MBy + 512 * 1024);
  u16* wvTh = (u16*)(wsb + 66 * MBy);
  u16* hB   = (u16*)(wsb + 64 * MBy);
  u16* w1T  = (u16*)(wsb + 96 * MBy);
  u16* w2T  = (u16*)(wsb + 98 * MBy);

  const long LO8 = 4194304;  // 8 MB in u16 elements (hi->lo offset)
  const long SD = (long)S * D, SSl = (long)S * S;

  // weight prep (k/q split, v hi-only) + embedding
  wt_k<<<1024, 256, 0, stream>>>(wk, wkTh, wkTl, 512, 512);
  wt_k<<<1024, 256, 0, stream>>>(wq, wqTh, wqTl, 512, 512);
  wt_k<<<1024, 256, 0, stream>>>(wv, wvTh, nullptr, 512, 512);
  embed_pos_k<<<BS, 256, 0, stream>>>(seq, emb, X, Xhi, Xlo);

  // k,q projections: split x split -> split output (3-pass MFMA)
  mm_k<1, 1, 2, 0><<<dim3(4, 64, 1), 256, 0, stream>>>(
      Xhi, wkTh, kHi, bk, BS, D, D, 0, 0, 0, LO8, 262144, LO8, 1.0f);
  mm_k<1, 1, 2, 0><<<dim3(4, 64, 1), 256, 0, stream>>>(
      Xhi, wqTh, qHi, bq, BS, D, D, 0, 0, 0, LO8, 262144, LO8, 1.0f);
  // v projection: plain bf16, transposed epilogue -> vT[z][D][S]
  mm_k<0, 0, 3, 0><<<dim3(4, 64, 1), 256, 0, stream>>>(
      Xhi, wvTh, vT, bv, BS, D, D, 0, 0, 0, 0, 0, 0, 1.0f);

  // scores = (k @ q^T) / sqrt(D), split x split, batched
  mm_k<1, 1, 0, 0><<<dim3(16, 16, BB), 256, 0, stream>>>(
      kHi, qHi, Sc, nullptr, S, S, D, SD, SD, SSl,
      LO8, LO8, 0, 0.044194173824159216f);

  softmax_k<<<BS, 256, 0, stream>>>(Sc);

  // attn = P @ v (A fp32 converted in staging, B = vT), batched
  mm_k<2, 0, 0, 0><<<dim3(4, 16, BB), 256, 0, stream>>>(
      Sc, vT, attn, nullptr, S, D, S, SSl, (long)D * S, SD, 0, 0, 0, 1.0f);

  // r = LN(x + attn) -> X (+ bf16 rB)
  ln_res_k<<<BS, 256, 0, stream>>>(X, attn, lng, lnb, rB);

  // FF weights (transposed, hi only) into freed Sc tail
  wt_k<<<4096, 256, 0, stream>>>(w1, w1T, nullptr, 512, 2048);
  wt_k<<<4096, 256, 0, stream>>>(w2, w2T, nullptr, 2048, 512);

  // h = gelu(r @ w1 + b1) -> bf16
  mm_k<0, 0, 1, 1><<<dim3(16, 64, 1), 256, 0, stream>>>(
      rB, w1T, hB, b1, BS, DFF, D, 0, 0, 0, 0, 0, 0, 1.0f);
  // ff = h @ w2 + b2 -> fp32
  mm_k<0, 0, 0, 0><<<dim3(4, 64, 1), 256, 0, stream>>>(
      hB, w2T, ff, b2, BS, D, DFF, 0, 0, 0, 0, 0, 0, 1.0f);

  // out = LN(r + ff)
  ln_out_k<<<BS, 256, 0, stream>>>(X, ff, lng, lnb, (float*)d_out);
}

// Round 4
// 504.454 us; speedup vs baseline: 2.7302x; 1.1362x over previous
//
#include <hip/hip_runtime.h>
#include <math.h>

static constexpr int BB  = 4;
static constexpr int S   = 2048;
static constexpr int D   = 512;
static constexpr int DFF = 2048;
static constexpr int BS  = BB * S;   // 8192 rows

using u16 = unsigned short;
using v8s = __attribute__((ext_vector_type(8))) short;
using v4f = __attribute__((ext_vector_type(4))) float;

__device__ __forceinline__ float bf2f(u16 h) {
  union { unsigned int u; float f; } c; c.u = ((unsigned int)h) << 16; return c.f;
}
__device__ __forceinline__ u16 f2bf(float f) {  // round-to-nearest-even
  union { float f; unsigned int u; } c; c.f = f;
  unsigned int r = c.u + 0x7FFF + ((c.u >> 16) & 1);
  return (u16)(r >> 16);
}

// async global->LDS, 16 B per lane; LDS dest is wave-uniform base + lane*16
__device__ __forceinline__ void async16(const void* g, void* l) {
  __builtin_amdgcn_global_load_lds(
      (const __attribute__((address_space(1))) unsigned int*)g,
      (__attribute__((address_space(3))) unsigned int*)l, 16, 0, 0);
}

// ---- block-wide reductions (block = 256 threads = 4 waves) ----
__device__ __forceinline__ float blockSum(float v) {
#pragma unroll
  for (int o = 32; o; o >>= 1) v += __shfl_xor(v, o, 64);
  __shared__ float t[4];
  __syncthreads();
  if ((threadIdx.x & 63) == 0) t[threadIdx.x >> 6] = v;
  __syncthreads();
  return t[0] + t[1] + t[2] + t[3];
}
__device__ __forceinline__ float blockMax(float v) {
#pragma unroll
  for (int o = 32; o; o >>= 1) v = fmaxf(v, __shfl_xor(v, o, 64));
  __shared__ float t[4];
  __syncthreads();
  if ((threadIdx.x & 63) == 0) t[threadIdx.x >> 6] = v;
  __syncthreads();
  return fmaxf(fmaxf(t[0], t[1]), fmaxf(t[2], t[3]));
}

// ---- embedding gather + positional encoding; fp32 + bf16 hi/lo split ----
__global__ __launch_bounds__(256) void embed_pos_k(
    const int* __restrict__ seq, const float* __restrict__ emb,
    float* __restrict__ X, u16* __restrict__ Xhi, u16* __restrict__ Xlo) {
  const int bs = blockIdx.x;
  const int s  = bs & (S - 1);
  const int idx = seq[bs];
  const float* er = emb + (size_t)idx * D;
#pragma unroll
  for (int t = 0; t < 2; ++t) {
    const int d = threadIdx.x + 256 * t;
    const double ang = (double)s / pow(10000.0, (2.0 * d) / (double)D);
    const float p = (d & 1) ? (float)cos(ang) : (float)sin(ang);
    const float val = (er[d] + p) * 22.62741699796952f;  // * sqrt(512)
    const size_t o = (size_t)bs * D + d;
    X[o] = val;
    const u16 hi = f2bf(val);
    Xhi[o] = hi;
    Xlo[o] = f2bf(val - bf2f(hi));
  }
}

// ---- weight transpose + bf16 split: W[K,N] fp32 -> T[N,K] bf16 ----
__global__ __launch_bounds__(256) void wt_k(
    const float* __restrict__ W, u16* __restrict__ Thi, u16* __restrict__ Tlo,
    int K, int N) {
  const int idx = blockIdx.x * 256 + threadIdx.x;
  const int k = idx / N, n = idx % N;
  const float v = W[idx];
  const u16 hi = f2bf(v);
  Thi[(long)n * K + k] = hi;
  if (Tlo) Tlo[(long)n * K + k] = f2bf(v - bf2f(hi));
}

// ---- MFMA GEMM: C[M,N] = act(scale * A @ B^T + bias), A,B bf16 (B as [N,K]) ----
// TM: 128 (waves 2x2 of 64x64) or 64 (waves 1x4 of 64x32); N-tile always 128.
// AMODE/BMODE: 0 = plain bf16, 1 = hi/lo split (lo at +aLo/+bLo) -> 3-pass MFMA
// OMODE: 0 = fp32, 1 = bf16, 2 = bf16 split (lo at +cLo), 3 = bf16 transposed
//        per-batch vT[z][n][m] (z = gm>>11) for the V projection
// ACT:   0 = none, 1 = exact GELU
// Staging: global_load_lds width 16, LDS pitch 32 u16 (no pad, m97 structure).
template <int TM, int AMODE, int BMODE, int OMODE, int ACT>
__global__ __launch_bounds__(256) void mm_k(
    const u16* __restrict__ Ap, const u16* __restrict__ Bp,
    void* __restrict__ Cp, const float* __restrict__ bias,
    int M, int N, int K, long sA, long sB, long sC,
    long aLo, long bLo, long cLo, float scale) {
  constexpr int NA = (AMODE == 1) ? 2 : 1;
  constexpr int NB = (BMODE == 1) ? 2 : 1;
  constexpr int ATE = TM * 32;
  constexpr int BTE = 128 * 32;
  __shared__ __align__(16) u16 lds[NA * ATE + NB * BTE];
  u16* const Ah = lds;
  u16* const Al = lds + ATE;
  u16* const Bh = lds + NA * ATE;
  u16* const Bl = lds + NA * ATE + BTE;

  const int tid = threadIdx.x, lane = tid & 63, w = tid >> 6;
  const int quad = lane >> 4, l16 = lane & 15;
  constexpr int MT = 4;
  constexpr int NT = (TM == 128) ? 4 : 2;
  constexpr int WN = (TM == 128) ? 64 : 32;
  const int wm = (TM == 128) ? (w >> 1) : 0;
  const int wn = (TM == 128) ? (w & 1) : w;
  const int m0 = blockIdx.y * TM, n0 = blockIdx.x * 128;

  const u16* A = Ap + (long)blockIdx.z * sA;
  const u16* B = Bp + (long)blockIdx.z * sB;

  v4f acc[MT][NT] = {};
  const int srow = lane >> 2, scol = (lane & 3) * 8;

  for (int k0 = 0; k0 < K; k0 += 32) {
    __syncthreads();
    // A tile(s): TM x 32, chunks of 16 rows (1024 B) per wave-issue
#pragma unroll
    for (int i = 0; i < TM / 64; ++i) {
      const int q = w + i * 4;
      const long go = (long)(m0 + q * 16 + srow) * K + k0 + scol;
      async16(A + go, Ah + q * 512);
      if constexpr (AMODE == 1) async16(A + aLo + go, Al + q * 512);
    }
    // B tile(s): 128 x 32
#pragma unroll
    for (int i = 0; i < 2; ++i) {
      const int q = w + i * 4;
      const long go = (long)(n0 + q * 16 + srow) * K + k0 + scol;
      async16(B + go, Bh + q * 512);
      if constexpr (BMODE == 1) async16(B + bLo + go, Bl + q * 512);
    }
    __syncthreads();

    v8s af[MT], bfr[NT], alo[MT], blo[NT];
#pragma unroll
    for (int t = 0; t < MT; ++t) {
      const int ao = (wm * 64 + t * 16 + l16) * 32 + quad * 8;
      af[t] = *(v8s*)&Ah[ao];
      if constexpr (AMODE == 1) alo[t] = *(v8s*)&Al[ao];
    }
#pragma unroll
    for (int t = 0; t < NT; ++t) {
      const int bo = (wn * WN + t * 16 + l16) * 32 + quad * 8;
      bfr[t] = *(v8s*)&Bh[bo];
      if constexpr (BMODE == 1) blo[t] = *(v8s*)&Bl[bo];
    }
#pragma unroll
    for (int mt = 0; mt < MT; ++mt)
#pragma unroll
      for (int nt = 0; nt < NT; ++nt) {
        acc[mt][nt] = __builtin_amdgcn_mfma_f32_16x16x32_bf16(
            af[mt], bfr[nt], acc[mt][nt], 0, 0, 0);
        if constexpr (AMODE == 1)
          acc[mt][nt] = __builtin_amdgcn_mfma_f32_16x16x32_bf16(
              alo[mt], bfr[nt], acc[mt][nt], 0, 0, 0);
        if constexpr (BMODE == 1)
          acc[mt][nt] = __builtin_amdgcn_mfma_f32_16x16x32_bf16(
              af[mt], blo[nt], acc[mt][nt], 0, 0, 0);
      }
  }

  // ---- epilogue (C layout: col = lane&15, row = quad*4 + reg) ----
  const long Cz = (long)blockIdx.z * sC;
#pragma unroll
  for (int nt = 0; nt < NT; ++nt) {
    const int gn = n0 + wn * WN + nt * 16 + l16;
    const float bv = bias ? bias[gn] : 0.0f;
#pragma unroll
    for (int mt = 0; mt < MT; ++mt) {
      const int gmb = m0 + wm * 64 + mt * 16 + quad * 4;
#pragma unroll
      for (int r = 0; r < 4; ++r) {
        const int gm = gmb + r;
        float v = acc[mt][nt][r] * scale + bv;
        if constexpr (ACT == 1)
          v = 0.5f * v * (1.0f + erff(v * 0.7071067811865476f));
        const long ci = Cz + (long)gm * N + gn;
        if constexpr (OMODE == 0) {
          ((float*)Cp)[ci] = v;
        } else if constexpr (OMODE == 1) {
          ((u16*)Cp)[ci] = f2bf(v);
        } else if constexpr (OMODE == 2) {
          const u16 hi = f2bf(v);
          ((u16*)Cp)[ci] = hi;
          ((u16*)Cp)[ci + cLo] = f2bf(v - bf2f(hi));
        } else {  // vT[z][gn][ml]
          const int z2 = gm >> 11, ml = gm & 2047;
          ((u16*)Cp)[((long)z2 * N + gn) * 2048 + ml] = f2bf(v);
        }
      }
    }
  }
}

// ---- row softmax over S=2048: read fp32 Sc, write bf16 P ----
__global__ __launch_bounds__(256) void softmax_k(
    const float* __restrict__ Sc, u16* __restrict__ P) {
  const float* p = Sc + (size_t)blockIdx.x * S;
  u16* po = P + (size_t)blockIdx.x * S;
  const int base = threadIdx.x * 8;
  const float4 a = *(const float4*)(p + base);
  const float4 b = *(const float4*)(p + base + 4);
  float v[8] = {a.x, a.y, a.z, a.w, b.x, b.y, b.z, b.w};
  float m = -1e30f;
#pragma unroll
  for (int i = 0; i < 8; ++i) m = fmaxf(m, v[i]);
  m = blockMax(m);
  float sum = 0.f;
#pragma unroll
  for (int i = 0; i < 8; ++i) { v[i] = expf(v[i] - m); sum += v[i]; }
  sum = blockSum(sum);
  const float inv = 1.0f / sum;
  v8s o;
#pragma unroll
  for (int i = 0; i < 8; ++i) o[i] = (short)f2bf(v[i] * inv);
  *(v8s*)(po + base) = o;
}

// ---- r = LayerNorm(X + Add) -> X (in place) + bf16 copy rB ----
__global__ __launch_bounds__(256) void ln_res_k(
    float* __restrict__ X, const float* __restrict__ Add,
    const float* __restrict__ g, const float* __restrict__ b,
    u16* __restrict__ rB) {
  float* xr = X + (size_t)blockIdx.x * D;
  const float* ar = Add + (size_t)blockIdx.x * D;
  u16* rb = rB + (size_t)blockIdx.x * D;
  const int t0 = threadIdx.x, t1 = threadIdx.x + 256;
  const float z0 = xr[t0] + ar[t0];
  const float z1 = xr[t1] + ar[t1];
  const float mu = blockSum(z0 + z1) * (1.0f / D);
  const float d0 = z0 - mu, d1 = z1 - mu;
  const float var = blockSum(d0 * d0 + d1 * d1) * (1.0f / D);
  const float rs = rsqrtf(var + 1e-5f);
  const float v0 = d0 * rs * g[t0] + b[t0];
  const float v1 = d1 * rs * g[t1] + b[t1];
  xr[t0] = v0; xr[t1] = v1;
  rb[t0] = f2bf(v0); rb[t1] = f2bf(v1);
}

// ---- out = LayerNorm(R + F), fp32 ----
__global__ __launch_bounds__(256) void ln_out_k(
    const float* __restrict__ R, const float* __restrict__ F,
    const float* __restrict__ g, const float* __restrict__ b,
    float* __restrict__ out) {
  const float* rr = R + (size_t)blockIdx.x * D;
  const float* fr = F + (size_t)blockIdx.x * D;
  float* orow = out + (size_t)blockIdx.x * D;
  const int t0 = threadIdx.x, t1 = threadIdx.x + 256;
  const float z0 = rr[t0] + fr[t0];
  const float z1 = rr[t1] + fr[t1];
  const float mu = blockSum(z0 + z1) * (1.0f / D);
  const float d0 = z0 - mu, d1 = z1 - mu;
  const float var = blockSum(d0 * d0 + d1 * d1) * (1.0f / D);
  const float rs = rsqrtf(var + 1e-5f);
  orow[t0] = d0 * rs * g[t0] + b[t0];
  orow[t1] = d1 * rs * g[t1] + b[t1];
}

extern "C" void kernel_launch(void* const* d_in, const int* in_sizes, int n_in,
                              void* d_out, int out_size, void* d_ws, size_t ws_size,
                              hipStream_t stream) {
  (void)in_sizes; (void)n_in; (void)out_size; (void)ws_size;
  const int*   seq = (const int*)d_in[0];
  const float* emb = (const float*)d_in[1];
  const float* wk  = (const float*)d_in[2];
  const float* bk  = (const float*)d_in[3];
  const float* wq  = (const float*)d_in[4];
  const float* bq  = (const float*)d_in[5];
  const float* wv  = (const float*)d_in[6];
  const float* bv  = (const float*)d_in[7];
  const float* lng = (const float*)d_in[8];
  const float* lnb = (const float*)d_in[9];
  const float* w1  = (const float*)d_in[10];
  const float* b1  = (const float*)d_in[11];
  const float* w2  = (const float*)d_in[12];
  const float* b2  = (const float*)d_in[13];

  // Workspace (MB offsets, lifetimes):
  //  [0,16)   X fp32 (x -> r in-place)
  //  [16,24)  Xhi        -> rB after projections
  //  [24,32)  Xlo        -> vT after k,q projections
  //  [32,48)  kHi|kLo    -> P bf16 [32,64) after scores -> ff fp32 [32,48) after PV
  //  [48,64)  qHi|qLo    (P tail)
  //  [64,128) Sc fp32; pre-scores: weight tiles at [64,67); post-softmax:
  //           attn [64,80); hB [80,112); w1T [112,114); w2T [114,116)
  const size_t MBy = 1024 * 1024;
  char* wsb = (char*)d_ws;
  float* X    = (float*)wsb;
  u16*   Xhi  = (u16*)(wsb + 16 * MBy);
  u16*   Xlo  = (u16*)(wsb + 24 * MBy);
  u16*   kHi  = (u16*)(wsb + 32 * MBy);
  u16*   qHi  = (u16*)(wsb + 48 * MBy);
  u16*   vT   = (u16*)(wsb + 24 * MBy);
  u16*   rB   = (u16*)(wsb + 16 * MBy);
  float* Sc   = (float*)(wsb + 64 * MBy);
  u16*   P    = (u16*)(wsb + 32 * MBy);
  float* attn = (float*)(wsb + 64 * MBy);
  u16*   hB   = (u16*)(wsb + 80 * MBy);
  u16*   w1T  = (u16*)(wsb + 112 * MBy);
  u16*   w2T  = (u16*)(wsb + 114 * MBy);
  float* ff   = (float*)(wsb + 32 * MBy);
  u16*   wkTh = (u16*)(wsb + 64 * MBy);
  u16*   wkTl = (u16*)(wsb + 64 * MBy + 512 * 1024);
  u16*   wqTh = (u16*)(wsb + 65 * MBy);
  u16*   wqTl = (u16*)(wsb + 65 * MBy + 512 * 1024);
  u16*   wvTh = (u16*)(wsb + 66 * MBy);

  const long LO8 = 4194304;  // 8 MB in u16 elements
  const long SD = (long)S * D, SSl = (long)S * S;

  wt_k<<<1024, 256, 0, stream>>>(wk, wkTh, wkTl, 512, 512);
  wt_k<<<1024, 256, 0, stream>>>(wq, wqTh, wqTl, 512, 512);
  wt_k<<<1024, 256, 0, stream>>>(wv, wvTh, nullptr, 512, 512);
  embed_pos_k<<<BS, 256, 0, stream>>>(seq, emb, X, Xhi, Xlo);

  // k,q projections: split x split (3-pass), TM=64 -> 512 blocks
  mm_k<64, 1, 1, 2, 0><<<dim3(4, 128, 1), 256, 0, stream>>>(
      Xhi, wkTh, kHi, bk, BS, D, D, 0, 0, 0, LO8, 262144, LO8, 1.0f);
  mm_k<64, 1, 1, 2, 0><<<dim3(4, 128, 1), 256, 0, stream>>>(
      Xhi, wqTh, qHi, bq, BS, D, D, 0, 0, 0, LO8, 262144, LO8, 1.0f);
  // v projection: plain bf16, transposed epilogue -> vT[z][D][S]
  mm_k<64, 0, 0, 3, 0><<<dim3(4, 128, 1), 256, 0, stream>>>(
      Xhi, wvTh, vT, bv, BS, D, D, 0, 0, 0, 0, 0, 0, 1.0f);

  // scores = (k @ q^T) / sqrt(D), split x split, batched, TM=128 -> 1024 blocks
  mm_k<128, 1, 1, 0, 0><<<dim3(16, 16, BB), 256, 0, stream>>>(
      kHi, qHi, Sc, nullptr, S, S, D, SD, SD, SSl,
      LO8, LO8, 0, 0.044194173824159216f);

  softmax_k<<<BS, 256, 0, stream>>>(Sc, P);

  // attn = P @ v (bf16 x bf16), batched, TM=64 -> 512 blocks
  mm_k<64, 0, 0, 0, 0><<<dim3(4, 32, BB), 256, 0, stream>>>(
      P, vT, attn, nullptr, S, D, S, SSl, (long)D * S, SD, 0, 0, 0, 1.0f);

  // r = LN(x + attn) -> X (+ bf16 rB)
  ln_res_k<<<BS, 256, 0, stream>>>(X, attn, lng, lnb, rB);

  wt_k<<<4096, 256, 0, stream>>>(w1, w1T, nullptr, 512, 2048);
  wt_k<<<4096, 256, 0, stream>>>(w2, w2T, nullptr, 2048, 512);

  // h = gelu(r @ w1 + b1) -> bf16, TM=128 -> 1024 blocks
  mm_k<128, 0, 0, 1, 1><<<dim3(16, 64, 1), 256, 0, stream>>>(
      rB, w1T, hB, b1, BS, DFF, D, 0, 0, 0, 0, 0, 0, 1.0f);
  // ff = h @ w2 + b2 -> fp32, TM=64 -> 512 blocks
  mm_k<64, 0, 0, 0, 0><<<dim3(4, 128, 1), 256, 0, stream>>>(
      hB, w2T, ff, b2, BS, D, DFF, 0, 0, 0, 0, 0, 0, 1.0f);

  // out = LN(r + ff)
  ln_out_k<<<BS, 256, 0, stream>>>(X, ff, lng, lnb, (float*)d_out);
}

// Round 5
// 437.759 us; speedup vs baseline: 3.1462x; 1.1524x over previous
//
#include <hip/hip_runtime.h>
#include <math.h>

static constexpr int BB  = 4;
static constexpr int S   = 2048;
static constexpr int D   = 512;
static constexpr int DFF = 2048;
static constexpr int BS  = BB * S;   // 8192 rows

using v8h = __attribute__((ext_vector_type(8))) _Float16;
using v4f = __attribute__((ext_vector_type(4))) float;

// async global->LDS, 16 B per lane; LDS dest = wave-uniform base + lane*16
__device__ __forceinline__ void async16(const void* g, void* l) {
  __builtin_amdgcn_global_load_lds(
      (const __attribute__((address_space(1))) unsigned int*)g,
      (__attribute__((address_space(3))) unsigned int*)l, 16, 0, 0);
}

// ---- block-wide reductions (block = 256 threads = 4 waves) ----
__device__ __forceinline__ float blockSum(float v) {
#pragma unroll
  for (int o = 32; o; o >>= 1) v += __shfl_xor(v, o, 64);
  __shared__ float t[4];
  __syncthreads();
  if ((threadIdx.x & 63) == 0) t[threadIdx.x >> 6] = v;
  __syncthreads();
  return t[0] + t[1] + t[2] + t[3];
}
__device__ __forceinline__ float blockMax(float v) {
#pragma unroll
  for (int o = 32; o; o >>= 1) v = fmaxf(v, __shfl_xor(v, o, 64));
  __shared__ float t[4];
  __syncthreads();
  if ((threadIdx.x & 63) == 0) t[threadIdx.x >> 6] = v;
  __syncthreads();
  return fmaxf(fmaxf(t[0], t[1]), fmaxf(t[2], t[3]));
}

// ---- embedding gather + positional encoding; fp32 + fp16 copy ----
__global__ __launch_bounds__(256) void embed_pos_k(
    const int* __restrict__ seq, const float* __restrict__ emb,
    float* __restrict__ X, _Float16* __restrict__ Xh) {
  const int bs = blockIdx.x;
  const int s  = bs & (S - 1);
  const int idx = seq[bs];
  const float* er = emb + (size_t)idx * D;
#pragma unroll
  for (int t = 0; t < 2; ++t) {
    const int d = threadIdx.x + 256 * t;
    const double ang = (double)s / pow(10000.0, (2.0 * d) / (double)D);
    const float p = (d & 1) ? (float)cos(ang) : (float)sin(ang);
    const float val = (er[d] + p) * 22.62741699796952f;  // * sqrt(512)
    const size_t o = (size_t)bs * D + d;
    X[o] = val;
    Xh[o] = (_Float16)val;
  }
}

// ---- weight transpose: W[K,N] fp32 -> T[N,K] fp16 ----
__global__ __launch_bounds__(256) void wt_k(
    const float* __restrict__ W, _Float16* __restrict__ T, int K, int N) {
  const int idx = blockIdx.x * 256 + threadIdx.x;
  const int k = idx / N, n = idx % N;
  T[(long)n * K + k] = (_Float16)W[idx];
}

// ---- MFMA GEMM: C[M,N] = act(scale * A @ B^T + bias), fp16 in, fp32 acc ----
// A[M,K], B[N,K] row-major fp16 (row stride = K). Tile TMx128, BK=64.
// TM: 128 (waves 2x2, each 64x64) or 64 (waves 1x4, each 64x32).
// OMODE: 0 = fp32, 1 = fp16, 3 = fp16 transposed per-batch vT[z][n][m], z=gm>>11
// ACT: 0 = none, 1 = exact GELU
// Staging: global_load_lds w16; XOR-swizzled 16B chunks (conflict-free reads).
template <int TM, int OMODE, int ACT>
__global__ __launch_bounds__(256) void mm_k(
    const _Float16* __restrict__ Ap, const _Float16* __restrict__ Bp,
    void* __restrict__ Cp, const float* __restrict__ bias,
    int N, int K, long sA, long sB, long sC, float scale) {
  constexpr int ATE = TM * 64;       // halfs
  constexpr int BTE = 128 * 64;
  __shared__ __align__(16) _Float16 lds[ATE + BTE];
  _Float16* const Ah = lds;
  _Float16* const Bh = lds + ATE;

  const int tid = threadIdx.x, lane = tid & 63, w = tid >> 6;
  const int quad = lane >> 4, l16 = lane & 15;
  constexpr int MT = 4;
  constexpr int NT = (TM == 128) ? 4 : 2;
  constexpr int WN = (TM == 128) ? 64 : 32;
  const int wm = (TM == 128) ? (w >> 1) : 0;
  const int wn = (TM == 128) ? (w & 1) : w;
  const int m0 = blockIdx.y * TM, n0 = blockIdx.x * 128;

  const _Float16* A = Ap + (long)blockIdx.z * sA;
  const _Float16* B = Bp + (long)blockIdx.z * sB;

  v4f acc[MT][NT] = {};
  // staging: issue covers 8 rows x 64 halfs; lane -> row lane>>3, chunk lane&7
  // XOR swizzle: source chunk = (lane&7) ^ (lane>>3)
  const int srow8 = lane >> 3;
  const int cs = (lane & 7) ^ srow8;
  const int lsw = l16 & 7;           // unswizzle key for fragment reads

  for (int k0 = 0; k0 < K; k0 += 64) {
    __syncthreads();
#pragma unroll
    for (int i = 0; i < TM / 32; ++i) {
      const int is = w + i * 4;
      async16(A + (long)(m0 + is * 8 + srow8) * K + k0 + cs * 8, Ah + is * 512);
    }
#pragma unroll
    for (int i = 0; i < 4; ++i) {
      const int is = w + i * 4;
      async16(B + (long)(n0 + is * 8 + srow8) * K + k0 + cs * 8, Bh + is * 512);
    }
    __syncthreads();

    v8h af[MT][2], bfr[NT][2];
#pragma unroll
    for (int mt = 0; mt < MT; ++mt) {
      const int rr = wm * 64 + mt * 16 + l16;
#pragma unroll
      for (int kk = 0; kk < 2; ++kk) {
        const int c = (kk * 4 + quad) ^ lsw;
        af[mt][kk] = *(v8h*)&Ah[rr * 64 + c * 8];
      }
    }
#pragma unroll
    for (int nt = 0; nt < NT; ++nt) {
      const int rn = wn * WN + nt * 16 + l16;
#pragma unroll
      for (int kk = 0; kk < 2; ++kk) {
        const int c = (kk * 4 + quad) ^ lsw;
        bfr[nt][kk] = *(v8h*)&Bh[rn * 64 + c * 8];
      }
    }
#pragma unroll
    for (int kk = 0; kk < 2; ++kk)
#pragma unroll
      for (int mt = 0; mt < MT; ++mt)
#pragma unroll
        for (int nt = 0; nt < NT; ++nt)
          acc[mt][nt] = __builtin_amdgcn_mfma_f32_16x16x32_f16(
              af[mt][kk], bfr[nt][kk], acc[mt][nt], 0, 0, 0);
  }

  // ---- epilogue (C layout: col = lane&15, row = quad*4 + reg) ----
  const long Cz = (long)blockIdx.z * sC;
#pragma unroll
  for (int nt = 0; nt < NT; ++nt) {
    const int gn = n0 + wn * WN + nt * 16 + l16;
    const float bv = bias ? bias[gn] : 0.0f;
#pragma unroll
    for (int mt = 0; mt < MT; ++mt) {
      const int gmb = m0 + wm * 64 + mt * 16 + quad * 4;
#pragma unroll
      for (int r = 0; r < 4; ++r) {
        const int gm = gmb + r;
        float v = acc[mt][nt][r] * scale + bv;
        if constexpr (ACT == 1)
          v = 0.5f * v * (1.0f + erff(v * 0.7071067811865476f));
        if constexpr (OMODE == 0) {
          ((float*)Cp)[Cz + (long)gm * N + gn] = v;
        } else if constexpr (OMODE == 1) {
          ((_Float16*)Cp)[Cz + (long)gm * N + gn] = (_Float16)v;
        } else {  // vT[z][gn][m-local]
          const int z2 = gm >> 11, ml = gm & 2047;
          ((_Float16*)Cp)[((long)z2 * N + gn) * 2048 + ml] = (_Float16)v;
        }
      }
    }
  }
}

// ---- row softmax over S=2048: fp16 logits -> fp16 probabilities ----
__global__ __launch_bounds__(256) void softmax_k(
    const _Float16* __restrict__ Sc, _Float16* __restrict__ P) {
  const _Float16* p = Sc + (size_t)blockIdx.x * S;
  _Float16* po = P + (size_t)blockIdx.x * S;
  const int base = threadIdx.x * 8;
  const v8h a = *(const v8h*)(p + base);
  float v[8];
#pragma unroll
  for (int i = 0; i < 8; ++i) v[i] = (float)a[i];
  float m = -1e30f;
#pragma unroll
  for (int i = 0; i < 8; ++i) m = fmaxf(m, v[i]);
  m = blockMax(m);
  float sum = 0.f;
#pragma unroll
  for (int i = 0; i < 8; ++i) { v[i] = expf(v[i] - m); sum += v[i]; }
  sum = blockSum(sum);
  const float inv = 1.0f / sum;
  v8h o;
#pragma unroll
  for (int i = 0; i < 8; ++i) o[i] = (_Float16)(v[i] * inv);
  *(v8h*)(po + base) = o;
}

// ---- r = LayerNorm(X + Add) -> X (in place) + fp16 copy rF ----
__global__ __launch_bounds__(256) void ln_res_k(
    float* __restrict__ X, const float* __restrict__ Add,
    const float* __restrict__ g, const float* __restrict__ b,
    _Float16* __restrict__ rF) {
  float* xr = X + (size_t)blockIdx.x * D;
  const float* ar = Add + (size_t)blockIdx.x * D;
  _Float16* rf = rF + (size_t)blockIdx.x * D;
  const int t0 = threadIdx.x, t1 = threadIdx.x + 256;
  const float z0 = xr[t0] + ar[t0];
  const float z1 = xr[t1] + ar[t1];
  const float mu = blockSum(z0 + z1) * (1.0f / D);
  const float d0 = z0 - mu, d1 = z1 - mu;
  const float var = blockSum(d0 * d0 + d1 * d1) * (1.0f / D);
  const float rs = rsqrtf(var + 1e-5f);
  const float v0 = d0 * rs * g[t0] + b[t0];
  const float v1 = d1 * rs * g[t1] + b[t1];
  xr[t0] = v0; xr[t1] = v1;
  rf[t0] = (_Float16)v0; rf[t1] = (_Float16)v1;
}

// ---- out = LayerNorm(R + F), fp32 ----
__global__ __launch_bounds__(256) void ln_out_k(
    const float* __restrict__ R, const float* __restrict__ F,
    const float* __restrict__ g, const float* __restrict__ b,
    float* __restrict__ out) {
  const float* rr = R + (size_t)blockIdx.x * D;
  const float* fr = F + (size_t)blockIdx.x * D;
  float* orow = out + (size_t)blockIdx.x * D;
  const int t0 = threadIdx.x, t1 = threadIdx.x + 256;
  const float z0 = rr[t0] + fr[t0];
  const float z1 = rr[t1] + fr[t1];
  const float mu = blockSum(z0 + z1) * (1.0f / D);
  const float d0 = z0 - mu, d1 = z1 - mu;
  const float var = blockSum(d0 * d0 + d1 * d1) * (1.0f / D);
  const float rs = rsqrtf(var + 1e-5f);
  orow[t0] = d0 * rs * g[t0] + b[t0];
  orow[t1] = d1 * rs * g[t1] + b[t1];
}

extern "C" void kernel_launch(void* const* d_in, const int* in_sizes, int n_in,
                              void* d_out, int out_size, void* d_ws, size_t ws_size,
                              hipStream_t stream) {
  (void)in_sizes; (void)n_in; (void)out_size; (void)ws_size;
  const int*   seq = (const int*)d_in[0];
  const float* emb = (const float*)d_in[1];
  const float* wk  = (const float*)d_in[2];
  const float* bk  = (const float*)d_in[3];
  const float* wq  = (const float*)d_in[4];
  const float* bq  = (const float*)d_in[5];
  const float* wv  = (const float*)d_in[6];
  const float* bv  = (const float*)d_in[7];
  const float* lng = (const float*)d_in[8];
  const float* lnb = (const float*)d_in[9];
  const float* w1  = (const float*)d_in[10];
  const float* b1  = (const float*)d_in[11];
  const float* w2  = (const float*)d_in[12];
  const float* b2  = (const float*)d_in[13];

  // Workspace (MB offsets, lifetimes):
  //  [0,16)    X fp32 (x -> r in-place)
  //  [16,24)   Xh fp16 (dead after v proj)
  //  [24,32)   kF fp16 (dead after scores)   -> rF fp16
  //  [32,40)   qF fp16 (dead after scores)   -> ff fp32 [32,48)
  //  [40,48)   vT fp16 [z][D][S]             (ff tail)
  //  [48,80)   Sc fp16 (dead after softmax)  -> attn fp32 [48,64)
  //  [80,112)  P fp16 (dead after PV)        -> hF fp16
  //  [112,119) weight tiles fp16: wkT 112, wqT 113, wvT 114, w1T 115, w2T 117
  const size_t MBy = 1024 * 1024;
  char* wsb = (char*)d_ws;
  float*    X    = (float*)wsb;
  _Float16* Xh   = (_Float16*)(wsb + 16 * MBy);
  _Float16* kF   = (_Float16*)(wsb + 24 * MBy);
  _Float16* qF   = (_Float16*)(wsb + 32 * MBy);
  _Float16* vT   = (_Float16*)(wsb + 40 * MBy);
  _Float16* Sc   = (_Float16*)(wsb + 48 * MBy);
  _Float16* P    = (_Float16*)(wsb + 80 * MBy);
  float*    attn = (float*)(wsb + 48 * MBy);
  _Float16* rF   = (_Float16*)(wsb + 24 * MBy);
  _Float16* hF   = (_Float16*)(wsb + 80 * MBy);
  float*    ff   = (float*)(wsb + 32 * MBy);
  _Float16* wkT  = (_Float16*)(wsb + 112 * MBy);
  _Float16* wqT  = (_Float16*)(wsb + 113 * MBy);
  _Float16* wvT  = (_Float16*)(wsb + 114 * MBy);
  _Float16* w1T  = (_Float16*)(wsb + 115 * MBy);
  _Float16* w2T  = (_Float16*)(wsb + 117 * MBy);

  const long SD = (long)S * D, SSl = (long)S * S;

  wt_k<<<1024, 256, 0, stream>>>(wk, wkT, 512, 512);
  wt_k<<<1024, 256, 0, stream>>>(wq, wqT, 512, 512);
  wt_k<<<1024, 256, 0, stream>>>(wv, wvT, 512, 512);
  wt_k<<<4096, 256, 0, stream>>>(w1, w1T, 512, 2048);
  wt_k<<<4096, 256, 0, stream>>>(w2, w2T, 2048, 512);
  embed_pos_k<<<BS, 256, 0, stream>>>(seq, emb, X, Xh);

  // projections (fp16 single-pass), TM=64 -> 512 blocks
  mm_k<64, 1, 0><<<dim3(4, 128, 1), 256, 0, stream>>>(
      Xh, wkT, kF, bk, D, D, 0, 0, 0, 1.0f);
  mm_k<64, 1, 0><<<dim3(4, 128, 1), 256, 0, stream>>>(
      Xh, wqT, qF, bq, D, D, 0, 0, 0, 1.0f);
  mm_k<64, 3, 0><<<dim3(4, 128, 1), 256, 0, stream>>>(
      Xh, wvT, vT, bv, D, D, 0, 0, 0, 1.0f);

  // scores = (k @ q^T)/sqrt(D) -> fp16, batched, TM=128 -> 1024 blocks
  mm_k<128, 1, 0><<<dim3(16, 16, BB), 256, 0, stream>>>(
      kF, qF, Sc, nullptr, S, D, SD, SD, SSl, 0.044194173824159216f);

  softmax_k<<<BS, 256, 0, stream>>>(Sc, P);

  // attn = P @ v, batched, TM=64 -> 512 blocks
  mm_k<64, 0, 0><<<dim3(4, 32, BB), 256, 0, stream>>>(
      P, vT, attn, nullptr, D, S, SSl, (long)D * S, SD, 1.0f);

  // r = LN(x + attn) -> X (+ fp16 rF)
  ln_res_k<<<BS, 256, 0, stream>>>(X, attn, lng, lnb, rF);

  // h = gelu(r @ w1 + b1) -> fp16, TM=128 -> 1024 blocks
  mm_k<128, 1, 1><<<dim3(16, 64, 1), 256, 0, stream>>>(
      rF, w1T, hF, b1, DFF, D, 0, 0, 0, 1.0f);
  // ff = h @ w2 + b2 -> fp32, TM=64 -> 512 blocks
  mm_k<64, 0, 0><<<dim3(4, 128, 1), 256, 0, stream>>>(
      hF, w2T, ff, b2, D, DFF, 0, 0, 0, 1.0f);

  // out = LN(r + ff)
  ln_out_k<<<BS, 256, 0, stream>>>(X, ff, lng, lnb, (float*)d_out);
}